// Round 1
// baseline (55.774 us; speedup 1.0000x reference)
//
#include <hip/hip_runtime.h>

// out[d][c][h][w] = (h < d) ? left[c][h][w] - right[c][h + 128 - d][w] : 0
// N=1, C=16, H=128, W=256, D=128 (disps -128..-1, shift = 128 - d)
// Output: (1, 128, 16, 128, 256) fp32 = 256 MiB. Pure streaming write.

__global__ __launch_bounds__(256) void CostDifference_kernel(
    const float4* __restrict__ left,
    const float4* __restrict__ right,
    float4* __restrict__ out) {
    // total float4 elements: 128 (d) * 16 (c) * 128 (h) * 64 (w4) = 16,777,216
    const int total = 128 * 16 * 128 * 64;
    const int stride = gridDim.x * blockDim.x;
    for (int v = blockIdx.x * blockDim.x + threadIdx.x; v < total; v += stride) {
        const int w4 = v & 63;          // w / 4
        const int h  = (v >> 6) & 127;
        const int c  = (v >> 13) & 15;
        const int d  = v >> 17;

        float4 o = make_float4(0.f, 0.f, 0.f, 0.f);
        if (h < d) {                    // valid iff h + (128 - d) < 128
            const int hs = h + 128 - d;
            const float4 l = left [(c * 128 + h ) * 64 + w4];
            const float4 r = right[(c * 128 + hs) * 64 + w4];
            o = make_float4(l.x - r.x, l.y - r.y, l.z - r.z, l.w - r.w);
        }
        out[v] = o;
    }
}

extern "C" void kernel_launch(void* const* d_in, const int* in_sizes, int n_in,
                              void* d_out, int out_size, void* d_ws, size_t ws_size,
                              hipStream_t stream) {
    const float4* left  = (const float4*)d_in[0];
    const float4* right = (const float4*)d_in[1];
    float4* out = (float4*)d_out;

    const int blocks = 2048;   // grid-stride; memory-bound streaming
    const int threads = 256;
    CostDifference_kernel<<<blocks, threads, 0, stream>>>(left, right, out);
}